// Round 5
// baseline (358.968 us; speedup 1.0000x reference)
//
#include <hip/hip_runtime.h>
#include <float.h>

// Problem constants: B=2, N=4096, K=20, H=384
// Inputs: fp32 arrays (values bf16-quantized by harness). Output: fp32.
#define NPTS_B 4096
#define NPTS 8192            // B*N
#define KNN 20
#define NSAMP (NPTS*KNN)     // 163840

typedef __attribute__((ext_vector_type(8))) short bf16x8;
typedef __attribute__((ext_vector_type(4))) float f32x4;

// -------- bf16 helpers (internal staging only) --------
static __device__ __forceinline__ float bf2f(unsigned short u) {
  return __uint_as_float(((unsigned int)u) << 16);
}
static __device__ __forceinline__ unsigned short f2bf(float f) {
  unsigned int u = __float_as_uint(f);
  u += 0x7fffu + ((u >> 16) & 1u);
  return (unsigned short)(u >> 16);
}
// async global->LDS 16B: wave-uniform LDS base + lane*16.
static __device__ __forceinline__ void gl_lds16(const void* g, void* l) {
  __builtin_amdgcn_global_load_lds(
      (const __attribute__((address_space(1))) unsigned int*)g,
      (__attribute__((address_space(3))) unsigned int*)l, 16, 0, 0);
}

// ============================================================
// K0: weight prep — W3 -> W3T bf16 [n][k]; W4 -> W4T bf16 [n][k];
// W2 (128x256) -> W2T bf16 [n=256][k=128]. All values bf16-grid -> EXACT.
// ============================================================
__global__ __launch_bounds__(256) void wprep_kernel(const float* __restrict__ W3,
                                                    const float* __restrict__ W4,
                                                    const float* __restrict__ W2,
                                                    unsigned short* __restrict__ W3T,
                                                    unsigned short* __restrict__ W4T,
                                                    unsigned short* __restrict__ W2T) {
  int id = blockIdx.x * 256 + threadIdx.x;
  if (id < 512*512) {
    int n = id >> 9, k = id & 511;
    W3T[id] = f2bf(W3[k*512 + n]);
  } else if (id < 512*512 + 384*512) {
    int id2 = id - 512*512;
    int n = id2 >> 9, k = id2 & 511;
    W4T[id2] = f2bf(W4[k*384 + n]);
  } else {
    int id2 = id - (512*512 + 384*512);   // < 256*128
    int n = id2 >> 7, k = id2 & 127;
    W2T[id2] = f2bf(W2[k*256 + n]);
  }
}

// ============================================================
// K1a (R19): xyzprep — SoA transpose + squared-norm precompute.
// xT[b] layout: [0..4095]=x, [4096..]=y, [8192..]=z, [12288..]=sq.
// sq computed with the EXACT expression/order knn used in-kernel
// ((x*x+y*y)+z*z, contract off) -> bit-identical keys.
// ============================================================
__global__ __launch_bounds__(256) void xyzprep_kernel(const float* __restrict__ xyz,
                                                      float* __restrict__ xT) {
#pragma clang fp contract(off)
  int j = blockIdx.x * 256 + threadIdx.x;   // 0..8191
  int b = j >> 12, jj = j & 4095;
  float x = xyz[j*3+0], y = xyz[j*3+1], z = xyz[j*3+2];
  float sq = (x*x + y*y) + z*z;
  float* base = xT + (size_t)b*16384;
  base[jj] = x; base[4096+jj] = y; base[8192+jj] = z; base[12288+jj] = sq;
}

// ============================================================
// K1 (R19): KNN via radix-select + rank-sort (one block per point).
// Same u64 (d2_bits<<32|j) keys as the old extract-min (identical
// ordering/tie-break): histogram key[31:20] -> threshold bin -> compact
// (~30 items) -> O(n^2) rank-sort. ~5 barriers vs 20.
// ============================================================
__global__ __launch_bounds__(256) void knn_kernel(const float* __restrict__ xyz,
                                                  const float* __restrict__ xT,
                                                  int* __restrict__ idx,
                                                  float* __restrict__ out_xyz) {
#pragma clang fp contract(off)
  int p = blockIdx.x;            // 0..8191
  int b = p >> 12;
  int base = b << 12;            // batch base row
  int tid = threadIdx.x;
  const float* xb = xT + (size_t)b*16384;
  float xi0 = xyz[p*3+0], xi1 = xyz[p*3+1], xi2 = xyz[p*3+2];
  float sqi = (xi0*xi0 + xi1*xi1) + xi2*xi2;

  __shared__ __align__(16) int hist[4096];      // 16 KB; aliased by list later
  __shared__ int sL1[256];
  __shared__ int nsel, binB;

#pragma unroll
  for (int u = 0; u < 16; ++u) hist[tid + (u << 8)] = 0;
  if (tid == 0) nsel = 0;
  __syncthreads();

  unsigned long long cand[16];
#pragma unroll
  for (int u = 0; u < 16; ++u) {
    int j = tid + (u << 8);
    float a0 = xb[j], a1 = xb[4096 + j], a2 = xb[8192 + j];
    float sqj = xb[12288 + j];
    float dt  = (xi0*a0 + xi1*a1) + xi2*a2;
    float d2  = (sqi + sqj) - 2.0f*dt;
    unsigned int kb = __float_as_uint(d2);
    cand[u] = ((unsigned long long)kb << 32) | (unsigned int)j;
    atomicAdd(&hist[kb >> 20], 1);
  }
  __syncthreads();

  // level-1 sums: each thread sums its 16 consecutive bins
  {
    int s = 0;
#pragma unroll
    for (int u = 0; u < 16; ++u) s += hist[tid*16 + u];
    sL1[tid] = s;
  }
  __syncthreads();

  // wave 0: 64 lanes x 4 sL1 (64 bins each) -> inclusive scan -> find B
  if (tid < 64) {
    int v = sL1[tid*4] + sL1[tid*4+1] + sL1[tid*4+2] + sL1[tid*4+3];
    int incl = v;
#pragma unroll
    for (int off = 1; off < 64; off <<= 1) {
      int t = __shfl_up(incl, off);
      if (tid >= off) incl += t;
    }
    unsigned long long ball = __ballot(incl >= KNN);   // nonempty: lane63 = 4096
    int L = __ffsll(ball) - 1;
    if (tid == L) {
      int cum = incl - v;             // count in lanes < L
      int bfound = -1;
      for (int t2 = 4*L; t2 < 4*L + 4; ++t2) {
        int s = sL1[t2];
        if (bfound < 0) {
          if (cum + s >= KNN) {
            for (int u = 0; u < 16; ++u) {
              int c = hist[t2*16 + u];
              if (cum + c >= KNN) { bfound = t2*16 + u; break; }
              cum += c;
            }
          } else {
            cum += s;
          }
        }
      }
      binB = bfound;
    }
  }
  __syncthreads();

  int B = binB;
  unsigned long long* list = (unsigned long long*)hist;   // cap 2048 (16 KB)
#pragma unroll
  for (int u = 0; u < 16; ++u) {
    if ((int)(unsigned int)(cand[u] >> 52) <= B) {        // key>>20 == cand>>52
      int pos = atomicAdd(&nsel, 1);
      if (pos < 2048) list[pos] = cand[u];
    }
  }
  __syncthreads();

  int n = nsel; if (n > 2048) n = 2048;                   // n >= 20 guaranteed
  for (int t = tid; t < n; t += 256) {
    unsigned long long me = list[t];
    int rank = 0;
    for (int i = 0; i < n; ++i) rank += (list[i] < me);   // broadcast reads
    if (rank < KNN) idx[p*20 + rank] = base + (int)(me & 0xffffffffu);
  }
  if (tid < 3) out_xyz[p*3 + tid] = xyz[p*3 + tid];   // exact fp32 copy
}

// ============================================================
// K2: BN1 stats via 6-dim edge moments (affine trick).
// ============================================================
__global__ __launch_bounds__(256) void h1_moments_kernel(const float* __restrict__ xyz,
                                                         const int* __restrict__ idx,
                                                         float* __restrict__ mbuck) {
  int tid = threadIdx.x, blk = blockIdx.x;   // 320 blocks x 512 samples
  float A[33] = {};
#pragma unroll
  for (int u = 0; u < 2; ++u) {
    int s = blk*512 + (u << 8) + tid;
    unsigned int p = (unsigned int)s / 20u;
    int jg = idx[s];
    float c0 = xyz[p*3+0], c1 = xyz[p*3+1], c2 = xyz[p*3+2];
    float e[6];
    e[0] = xyz[jg*3+0] - c0; e[1] = xyz[jg*3+1] - c1; e[2] = xyz[jg*3+2] - c2;
    e[3] = c0; e[4] = c1; e[5] = c2;
    int k = 6;
#pragma unroll
    for (int d = 0; d < 6; ++d) {
      A[d] += e[d];
#pragma unroll
      for (int d2 = d; d2 < 6; ++d2) { A[k] = fmaf(e[d], e[d2], A[k]); ++k; }
    }
  }
#pragma unroll
  for (int off = 1; off < 64; off <<= 1) {
#pragma unroll
    for (int i = 0; i < 33; ++i) A[i] += __shfl_xor(A[i], off);
  }
  if ((tid & 63) == 0) {
    int b = ((blk << 2) | (tid >> 6)) & 15;
    for (int i = 0; i < 33; ++i) atomicAdd(&mbuck[b*64 + i], A[i]);
  }
}

__global__ void bn_prep1(const float* __restrict__ W1, const float* __restrict__ b1,
                         const float* __restrict__ g1, const float* __restrict__ be1,
                         const float* __restrict__ mbuck, float* __restrict__ misc) {
  __shared__ float red[33];
  int tid = threadIdx.x;  // 128
  if (tid < 33) {
    float s = 0.f;
    for (int b = 0; b < 16; ++b) s += mbuck[b*64 + tid];
    red[tid] = s;
  }
  __syncthreads();
  int c = tid;
  float w[6];
#pragma unroll
  for (int d = 0; d < 6; ++d) w[d] = W1[d*128 + c];
  const float inv = 1.0f / (float)NSAMP;
  float t = 0.f;
#pragma unroll
  for (int d = 0; d < 6; ++d) t = fmaf(w[d], red[d], t);
  t *= inv;
  float Q = 0.f;
  int k = 6;
#pragma unroll
  for (int d = 0; d < 6; ++d) {
#pragma unroll
    for (int d2 = d; d2 < 6; ++d2) {
      float coef = (d == d2) ? w[d]*w[d] : 2.f*w[d]*w[d2];
      Q = fmaf(coef, red[k], Q); ++k;
    }
  }
  Q *= inv;
  float var = Q - t*t;
  float mu = b1[c] + t;
  float a = g1[c] / sqrtf(var + 1e-5f);
  misc[c] = a;
  misc[128 + c] = be1[c] - mu*a;
}

// ============================================================
// K4: MFMA h2: per block of 4 points (M=80): edge -> h1 (BN1+ReLU, bf16
// into LDS A-tile) -> h2 = h1 @ W2T via MFMA (N=256, K=128) -> +b2 ->
// h2 bf16 store + fused per-point gmax.
// ============================================================
__global__ __launch_bounds__(256) void h2_kernel(const float* __restrict__ xyz,
                                                 const int* __restrict__ idx,
                                                 const float* __restrict__ W1,
                                                 const float* __restrict__ b1,
                                                 const unsigned short* __restrict__ W2T,
                                                 const float* __restrict__ b2,
                                                 const float* __restrict__ misc,
                                                 unsigned short* __restrict__ h2out,
                                                 unsigned short* __restrict__ gmaxout) {
  int p0 = blockIdx.x << 2;          // 4 points
  int tid = threadIdx.x;
  int w = tid >> 6, lane = tid & 63;
  int lr = lane & 15, lg = lane >> 4;
  __shared__ float e[80][6];
  __shared__ __align__(16) unsigned short As[80][136];
  __shared__ float pool[20][264];

  bf16x8 bfr[4][4];
#pragma unroll
  for (int j = 0; j < 4; ++j)
#pragma unroll
    for (int kk = 0; kk < 4; ++kk)
      bfr[j][kk] = *(const bf16x8*)(W2T + (size_t)(w*64 + j*16 + lr)*128 + kk*32 + lg*8);

  if (tid < 80) {
    int pl = (unsigned int)tid / 20u;
    int p = p0 + pl;
    int jg = idx[p0*20 + tid];
    float xi0 = xyz[p*3+0], xi1 = xyz[p*3+1], xi2 = xyz[p*3+2];
    e[tid][0] = xyz[jg*3+0] - xi0;
    e[tid][1] = xyz[jg*3+1] - xi1;
    e[tid][2] = xyz[jg*3+2] - xi2;
    e[tid][3] = xi0; e[tid][4] = xi1; e[tid][5] = xi2;
  }
  __syncthreads();

  {
    int c = tid & 127, half = tid >> 7;
    float w1v[6];
#pragma unroll
    for (int d = 0; d < 6; ++d) w1v[d] = W1[d*128 + c];
    float b1v = b1[c], a1 = misc[c], d1 = misc[128 + c];
#pragma unroll
    for (int u = 0; u < 40; ++u) {
      int row = (u << 1) | half;
      float v = b1v;
#pragma unroll
      for (int d = 0; d < 6; ++d) v = fmaf(e[row][d], w1v[d], v);
      v = fmaxf(fmaf(a1, v, d1), 0.f);
      As[row][c] = f2bf(v);
    }
  }
  __syncthreads();

  f32x4 acc[5][4] = {};
#pragma unroll
  for (int kk = 0; kk < 4; ++kk) {
    bf16x8 a[5];
#pragma unroll
    for (int i = 0; i < 5; ++i)
      a[i] = *(const bf16x8*)&As[i*16 + lr][kk*32 + lg*8];
#pragma unroll
    for (int i = 0; i < 5; ++i)
#pragma unroll
      for (int j = 0; j < 4; ++j)
        acc[i][j] = __builtin_amdgcn_mfma_f32_16x16x32_bf16(a[i], bfr[j][kk], acc[i][j], 0, 0, 0);
  }

  float b2v[4];
#pragma unroll
  for (int j = 0; j < 4; ++j) b2v[j] = b2[w*64 + j*16 + lr];
#pragma unroll
  for (int i = 0; i < 5; ++i) {
    int rbase = p0*20 + i*16 + lg*4;
#pragma unroll
    for (int j = 0; j < 4; ++j) {
      int col = w*64 + j*16 + lr;
      float v0 = acc[i][j][0] + b2v[j];
      float v1 = acc[i][j][1] + b2v[j];
      float v2 = acc[i][j][2] + b2v[j];
      float v3 = acc[i][j][3] + b2v[j];
      h2out[(size_t)(rbase+0)*256 + col] = f2bf(v0);
      h2out[(size_t)(rbase+1)*256 + col] = f2bf(v1);
      h2out[(size_t)(rbase+2)*256 + col] = f2bf(v2);
      h2out[(size_t)(rbase+3)*256 + col] = f2bf(v3);
      pool[i*4 + lg][col] = fmaxf(fmaxf(v0, v1), fmaxf(v2, v3));
    }
  }
  __syncthreads();
#pragma unroll
  for (int l = 0; l < 4; ++l) {
    int id = tid + (l << 8);        // 0..1023 : 4 points x 256 cols
    int q = id >> 8, col = id & 255;
    float v = pool[q*5][col];
#pragma unroll
    for (int u = 1; u < 5; ++u) v = fmaxf(v, pool[q*5 + u][col]);
    gmaxout[(size_t)(p0 + q)*256 + col] = f2bf(v);
  }
}

// ============================================================
// K5a (R18): pgemm — Pg = gmax @ W3a  (8192 x 512 x 256, bf16 MFMA).
// Computed once (256 blocks) instead of per-gemm3-block.
// ============================================================
__global__ __launch_bounds__(256) void pgemm_kernel(const unsigned short* __restrict__ gmax,
                                                    const unsigned short* __restrict__ W3T,
                                                    unsigned short* __restrict__ Pg) {
  int bid = blockIdx.x;             // 256 = 128 m * 2 n
  int bm = bid >> 1, bn = bid & 1;
  int m0 = bm << 6, n0 = bn << 8;
  int tid = threadIdx.x;
  int lane = tid & 63, w = tid >> 6;   // 4 waves, wave = n-column
  int lr = lane & 15, lg = lane >> 4;
  __shared__ __align__(16) char smem[40960];
  unsigned short (*As)[64] = (unsigned short (*)[64])smem;              // 64*64*2  = 8192
  unsigned short (*Bs)[64] = (unsigned short (*)[64])(smem + 8192);     // 256*64*2 = 32768
  unsigned short (*Cs)[264] = (unsigned short (*)[264])smem;            // 33792 (alias)

  int swz = lr >> 1;
  f32x4 acc[4][4] = {};
  for (int kc = 0; kc < 256; kc += 64) {
#pragma unroll
    for (int l = 0; l < 2; ++l) {
      int id = tid + (l << 8);
      int row = id >> 3, ks = id & 7, kg = ks ^ ((id >> 4) & 7);
      gl_lds16(gmax + (size_t)(m0 + row)*256 + kc + (kg << 3), &As[row][ks << 3]);
    }
#pragma unroll
    for (int l = 0; l < 8; ++l) {
      int id = tid + (l << 8);
      int row = id >> 3, ks = id & 7, kg = ks ^ ((id >> 4) & 7);
      gl_lds16(W3T + (size_t)(n0 + row)*512 + kc + (kg << 3), &Bs[row][ks << 3]);
    }
    __syncthreads();
#pragma unroll
    for (int h = 0; h < 2; ++h) {
      int ch = ((h << 2) | lg) ^ swz;
      bf16x8 a[4], b[4];
#pragma unroll
      for (int t = 0; t < 4; ++t)
        a[t] = *(const bf16x8*)&As[t*16 + lr][ch << 3];
#pragma unroll
      for (int t = 0; t < 4; ++t)
        b[t] = *(const bf16x8*)&Bs[w*64 + t*16 + lr][ch << 3];
#pragma unroll
      for (int i = 0; i < 4; ++i)
#pragma unroll
        for (int j = 0; j < 4; ++j)
          acc[i][j] = __builtin_amdgcn_mfma_f32_16x16x32_bf16(a[i], b[j], acc[i][j], 0, 0, 0);
    }
    __syncthreads();
  }
#pragma unroll
  for (int i = 0; i < 4; ++i)
#pragma unroll
    for (int j = 0; j < 4; ++j)
#pragma unroll
      for (int r = 0; r < 4; ++r)
        Cs[i*16 + lg*4 + r][w*64 + j*16 + lr] = f2bf(acc[i][j][r]);
  __syncthreads();
#pragma unroll
  for (int l = 0; l < 8; ++l) {
    int id = tid + (l << 8);          // 0..2047 : row = id>>5, chunk = id&31
    int row = id >> 5, chk = id & 31;
    *(uint4*)(Pg + (size_t)(m0 + row)*512 + n0 + (chk << 3)) =
        *(const uint4*)&Cs[row][chk << 3];
  }
}

// ============================================================
// K5: MFMA GEMM: h3 = h2 @ W3b + b3 + Pg (163840x512x256), bf16 MFMA.
// R18: pure single-phase K=256 loop (4 iters of proven R15 BK=64 body),
// Pg read in epilogue. R15 coalesced Cs store kept.
// ============================================================
__global__ __launch_bounds__(512, 4) void gemm3_kernel(const unsigned short* __restrict__ h2,
                                                       const unsigned short* __restrict__ Pg,
                                                       const unsigned short* __restrict__ W3T,
                                                       const float* __restrict__ b3,
                                                       unsigned short* __restrict__ h3,
                                                       float* __restrict__ s3buck) {
  int bid = blockIdx.x;               // 2560 = 160 grp * (2 bn * 8 x)
  int grp = bid >> 4, rem = bid & 15;
  int bn = rem >> 3;                  // 0..1
  int bm = (grp << 3) | (rem & 7);    // 0..1279
  int m0 = bm << 7, n0 = bn << 8;
  int tid = threadIdx.x;
  int lane = tid & 63, w = tid >> 6;  // 8 waves
  int mw = w >> 2, nw = w & 3;        // 2m x 4n
  int lr = lane & 15, lg = lane >> 4;
  __shared__ __align__(16) char smem[51200];
  unsigned short (*As)[64] = (unsigned short (*)[64])smem;              // 16384 B
  unsigned short (*Bs)[64] = (unsigned short (*)[64])(smem + 16384);    // 32768 B
  float* ssum = (float*)(smem + 49152);                                 // 1024 B
  float* ssq  = ssum + 256;                                             // 1024 B -> 51200
  unsigned short (*Cs)[264] = (unsigned short (*)[264])smem;            // 33792 B (aliases As+Bs)

  int rS[4], ksS[4], kgS[4];
#pragma unroll
  for (int l = 0; l < 4; ++l) {
    int id = tid + (l << 9);
    rS[l] = id >> 3;
    ksS[l] = id & 7;
    kgS[l] = ksS[l] ^ ((id >> 4) & 7);
  }
  int swz = lr >> 1;

  // ---- main loop: h3-partial = h2 @ W3b (K = 256..511) ----
  f32x4 acc[4][4] = {};
  for (int kc = 0; kc < 256; kc += 64) {
#pragma unroll
    for (int l = 0; l < 2; ++l)
      gl_lds16(h2 + (size_t)(m0 + rS[l])*256 + kc + (kgS[l] << 3), &As[rS[l]][ksS[l] << 3]);
#pragma unroll
    for (int l = 0; l < 4; ++l)
      gl_lds16(W3T + (size_t)(n0 + rS[l])*512 + (kc + 256) + (kgS[l] << 3), &Bs[rS[l]][ksS[l] << 3]);
    __syncthreads();
#pragma unroll
    for (int h = 0; h < 2; ++h) {
      int ch = ((h << 2) | lg) ^ swz;
      bf16x8 a[4], b[4];
#pragma unroll
      for (int t = 0; t < 4; ++t)
        a[t] = *(const bf16x8*)&As[mw*64 + t*16 + lr][ch << 3];
#pragma unroll
      for (int t = 0; t < 4; ++t)
        b[t] = *(const bf16x8*)&Bs[nw*64 + t*16 + lr][ch << 3];
#pragma unroll
      for (int i = 0; i < 4; ++i)
#pragma unroll
        for (int j = 0; j < 4; ++j)
          acc[i][j] = __builtin_amdgcn_mfma_f32_16x16x32_bf16(a[i], b[j], acc[i][j], 0, 0, 0);
    }
    __syncthreads();
  }

  // ---- Epilogue: v = acc + b3 + Pg[pt]; stats; COALESCED store via Cs ----
  if (tid < 256) { ssum[tid] = 0.f; ssq[tid] = 0.f; }
  __syncthreads();
  unsigned int pt[4][4];
#pragma unroll
  for (int i = 0; i < 4; ++i) {
    int rbase = m0 + mw*64 + i*16 + lg*4;
#pragma unroll
    for (int r = 0; r < 4; ++r)
      pt[i][r] = (unsigned int)(rbase + r) / 20u;
  }
#pragma unroll
  for (int half = 0; half < 2; ++half) {
    if (mw == half) {
#pragma unroll
      for (int j = 0; j < 4; ++j) {
        int colL = nw*64 + j*16 + lr;
        float b3v = b3[n0 + colL];
        float sumv = 0.f, sqv = 0.f;
#pragma unroll
        for (int i = 0; i < 4; ++i) {
#pragma unroll
          for (int r = 0; r < 4; ++r) {
            float v = acc[i][j][r] + b3v +
                      bf2f(Pg[(size_t)pt[i][r]*512 + n0 + colL]);
            Cs[i*16 + lg*4 + r][colL] = f2bf(v);
            sumv += v; sqv = fmaf(v, v, sqv);
          }
        }
        sumv += __shfl_xor(sumv, 16); sumv += __shfl_xor(sumv, 32);
        sqv  += __shfl_xor(sqv, 16);  sqv  += __shfl_xor(sqv, 32);
        if (lg == 0) {
          atomicAdd(&ssum[colL], sumv);
          atomicAdd(&ssq[colL], sqv);
        }
      }
    }
    __syncthreads();
#pragma unroll
    for (int l = 0; l < 4; ++l) {
      int id = tid + (l << 9);          // 0..2047 : row = id>>5, chunk = id&31
      int row = id >> 5, chk = id & 31;
      *(uint4*)(h3 + (size_t)(m0 + half*64 + row)*512 + n0 + (chk << 3)) =
          *(const uint4*)&Cs[row][chk << 3];
    }
    __syncthreads();
  }
  if (tid < 256) {
    int bkt = (bid & 63) * 1024;
    atomicAdd(&s3buck[bkt + n0 + tid], ssum[tid]);
    atomicAdd(&s3buck[bkt + 512 + n0 + tid], ssq[tid]);
  }
}

__global__ void bn_prep3(const float* __restrict__ g3, const float* __restrict__ be3,
                         const float* __restrict__ s3buck, float* __restrict__ misc) {
  int c = threadIdx.x;  // 512
  float s = 0.f, q = 0.f;
  for (int b = 0; b < 64; ++b) { s += s3buck[b*1024 + c]; q += s3buck[b*1024 + 512 + c]; }
  const float inv = 1.0f / (float)NSAMP;
  float mu = s * inv;
  float var = q * inv - mu * mu;
  float a = g3[c] / sqrtf(var + 1e-5f);
  misc[256 + c] = a;
  misc[768 + c] = be3[c] - mu * a;
}

// ============================================================
// K7: MFMA GEMM: h4 = relu(a3*h3+d3) @ W4 (+b4), fused max-pool over K=20.
// R20: ported gemm3's proven BK=64 body. Old: BK=32, 16 iters of
// {stage 24.5KB B + dequant -> drain -> 15 MFMA/wave -> drain}, pad-40
// As -> MfmaUtil 30%, 7.05M bank conflicts, 91.5 µs. New: BK=64, 8
// iters, 30 MFMA/wave/iter; As[80][64]/Bs[384][64] 128B rows with the
// verified (row>>1)&7 XOR chunk swizzle on BOTH store and read (rule
// 21; (id>>4)&7 == lr>>1 identity holds: all row-group strides are
// multiples of 8 rows). A stays reg-prefetch + BN3 dequant (aR0 all,
// aR1 tid<128). LDS 63.5KB (pool aliases As+Bs; af/df in tail) -> 2
// blocks/CU = current VGPR-limited occupancy. launch_bounds(512,4)
// pins unified VGPR+AGPR <= 128 (measured 120 at BK=32; +4 for aR1).
// ============================================================
__global__ __launch_bounds__(512, 4) void gemm4_kernel(const unsigned short* __restrict__ h3,
                                                       const unsigned short* __restrict__ W4T,
                                                       const float* __restrict__ b4,
                                                       const float* __restrict__ misc,
                                                       float* __restrict__ outf) {
  int bm = blockIdx.x;              // 2048 blocks: 4 points each
  int m0 = bm * 80;
  int tid = threadIdx.x;
  int lane = tid & 63, w = tid >> 6;     // w = column wave 0..7
  int lr = lane & 15, lg = lane >> 4;
  __shared__ __align__(16) char smem[63488];
  unsigned short (*As)[64] = (unsigned short (*)[64])smem;            // 80*128  = 10240 B
  unsigned short (*Bs)[64] = (unsigned short (*)[64])(smem + 10240);  // 384*128 = 49152 B -> 59392
  float (*pool)[392] = (float (*)[392])smem;                          // 31360 B (alias)
  float* af = (float*)(smem + 59392);                                 // 512 f32
  float* df = af + 512;                                               // 512 f32  -> ends 63488
  if (tid < 512) {
    af[tid] = misc[256 + tid];
    df[tid] = misc[768 + tid];
  }
  __syncthreads();
  f32x4 acc[5][3] = {};

  // A staging coords: 640 uint4/iter (80 rows x 8 chunks).
  // aR0: chunk tid (rows 0..63); aR1: chunk 512+tid, tid<128 (rows 64..79).
  // phys chunk ks = tid&7; global chunk kg = ks ^ ((row>>1)&7); row>>1 of
  // (64+row) has same &7 (64 ≡ 0 mod 16 rows).
  int arow = tid >> 3, aks = tid & 7, akg = aks ^ ((tid >> 4) & 7);
  uint4 aR0, aR1;
  aR0 = *(const uint4*)(h3 + (size_t)(m0 + arow)*512 + (akg << 3));
  if (tid < 128)
    aR1 = *(const uint4*)(h3 + (size_t)(m0 + 64 + arow)*512 + (akg << 3));

  for (int kc = 0; kc < 512; kc += 64) {
    // --- stage B: 384 rows x 8 chunks = 3072 gl_lds16, XOR-swizzled ---
#pragma unroll
    for (int l = 0; l < 6; ++l) {
      int id = tid + (l << 9);
      int row = id >> 3, ks = id & 7, kg = ks ^ ((id >> 4) & 7);
      gl_lds16(W4T + (size_t)row*512 + kc + (kg << 3), &Bs[row][ks << 3]);
    }
    // --- stage A: dequant BN3 affine + relu, repack bf16, swizzled ---
    {
      int k0 = kc + (akg << 3);
      unsigned int o[4];
#pragma unroll
      for (int q = 0; q < 4; ++q) {
        unsigned int u = ((const unsigned int*)&aR0)[q];
        float lo = bf2f((unsigned short)(u & 0xffffu));
        float hi = bf2f((unsigned short)(u >> 16));
        lo = fmaxf(fmaf(af[k0 + q*2],     lo, df[k0 + q*2]),     0.f);
        hi = fmaxf(fmaf(af[k0 + q*2 + 1], hi, df[k0 + q*2 + 1]), 0.f);
        o[q] = (unsigned int)f2bf(lo) | ((unsigned int)f2bf(hi) << 16);
      }
      *(uint4*)&As[arow][aks << 3] = *(const uint4*)o;
      if (tid < 128) {
        unsigned int o1[4];
#pragma unroll
        for (int q = 0; q < 4; ++q) {
          unsigned int u = ((const unsigned int*)&aR1)[q];
          float lo = bf2f((unsigned short)(u & 0xffffu));
          float hi = bf2f((unsigned short)(u >> 16));
          lo = fmaxf(fmaf(af[k0 + q*2],     lo, df[k0 + q*2]),     0.f);
          hi = fmaxf(fmaf(af[k0 + q*2 + 1], hi, df[k0 + q*2 + 1]), 0.f);
          o1[q] = (unsigned int)f2bf(lo) | ((unsigned int)f2bf(hi) << 16);
        }
        *(uint4*)&As[64 + arow][aks << 3] = *(const uint4*)o1;
      }
    }
    __syncthreads();
    // --- prefetch next A ---
    int kn = kc + 64;
    if (kn < 512) {
      aR0 = *(const uint4*)(h3 + (size_t)(m0 + arow)*512 + kn + (akg << 3));
      if (tid < 128)
        aR1 = *(const uint4*)(h3 + (size_t)(m0 + 64 + arow)*512 + kn + (akg << 3));
    }
    // --- fragments + MFMA: 2 halves x 15 ---
#pragma unroll
    for (int h = 0; h < 2; ++h) {
      int ch = ((h << 2) | lg) ^ (lr >> 1);
      bf16x8 a[5], b[3];
#pragma unroll
      for (int t = 0; t < 5; ++t)
        a[t] = *(const bf16x8*)&As[t*16 + lr][ch << 3];
#pragma unroll
      for (int t = 0; t < 3; ++t)
        b[t] = *(const bf16x8*)&Bs[w*48 + t*16 + lr][ch << 3];
#pragma unroll
      for (int i = 0; i < 5; ++i)
#pragma unroll
        for (int j = 0; j < 3; ++j)
          acc[i][j] = __builtin_amdgcn_mfma_f32_16x16x32_bf16(a[i], b[j], acc[i][j], 0, 0, 0);
    }
    __syncthreads();
  }

  // fused max-pool: per-lane reg-max (4 rows, point-pure since 4|20)
#pragma unroll
  for (int i = 0; i < 5; ++i)
#pragma unroll
    for (int j = 0; j < 3; ++j) {
      float m = fmaxf(fmaxf(acc[i][j][0], acc[i][j][1]),
                      fmaxf(acc[i][j][2], acc[i][j][3]));
      pool[i*4 + lg][w*48 + j*16 + lr] = m;
    }
  __syncthreads();
#pragma unroll
  for (int l = 0; l < 3; ++l) {
    int id = tid + (l << 9);            // 0..1535 : 4 points x 384 cols
    int q = id / 384, c = id - q*384;
    float v = pool[q*5][c];
#pragma unroll
    for (int u = 1; u < 5; ++u) v = fmaxf(v, pool[q*5 + u][c]);
    outf[(size_t)(bm*4 + q)*384 + c] = v + b4[c];
  }
}

// ============================================================
// Workspace layout:
//   0x0000000  idx        640 KB
//   0x00A0000  misc       1280 f32
//   0x00A2000  mbuck      16*64 f32 = 4 KB (zeroed)
//   0x00AA000  s3buck     256 KB  (zeroed)
//   0x00F0000  W3T bf16   512 KB
//   0x0170000  W4T bf16   384 KB
//   0x01D0000  W2T bf16   64 KB
//   0x0200000  gmax bf16  4 MB
//   0x0600000  h2   bf16  80 MB
//   0x5600000  h3   bf16  160 MB
//   0xF600000  Pg   bf16  8 MB
//   0xFE00000  xT   f32   128 KB  -> end 0xFE20000
// ============================================================
extern "C" void kernel_launch(void* const* d_in, const int* in_sizes, int n_in,
                              void* d_out, int out_size, void* d_ws, size_t ws_size,
                              hipStream_t stream) {
  const float* xyz = (const float*)d_in[0];
  const float* W1  = (const float*)d_in[1];
  const float* b1  = (const float*)d_in[2];
  const float* g1  = (const float*)d_in[3];
  const float* be1 = (const float*)d_in[4];
  const float* W2  = (const float*)d_in[5];
  const float* b2  = (const float*)d_in[6];
  const float* W3  = (const float*)d_in[7];
  const float* b3  = (const float*)d_in[8];
  const float* g3  = (const float*)d_in[9];
  const float* be3 = (const float*)d_in[10];
  const float* W4  = (const float*)d_in[11];
  const float* b4  = (const float*)d_in[12];

  char* ws = (char*)d_ws;
  int*            idx    = (int*)ws;
  float*          misc   = (float*)(ws + 0xA0000);
  float*          mbuck  = (float*)(ws + 0xA2000);
  float*          s3buck = (float*)(ws + 0xAA000);
  unsigned short* W3T    = (unsigned short*)(ws + 0xF0000);
  unsigned short* W4T    = (unsigned short*)(ws + 0x170000);
  unsigned short* W2T    = (unsigned short*)(ws + 0x1D0000);
  unsigned short* gmax   = (unsigned short*)(ws + 0x200000);
  unsigned short* h2     = (unsigned short*)(ws + 0x600000);
  unsigned short* h3     = (unsigned short*)(ws + 0x5600000ULL);
  unsigned short* Pg     = (unsigned short*)(ws + 0xF600000ULL);
  float*          xT     = (float*)(ws + 0xFE00000ULL);

  float* ofp   = (float*)d_out;
  float* oxyz  = ofp;             // 24576 fp32
  float* ofeat = ofp + 24576;     // 8192*384 fp32

  hipMemsetAsync(ws + 0xA2000, 0, 0x48000, stream);   // zero mbuck + s3buck

  wprep_kernel<<<(512*512 + 384*512 + 256*128)/256, 256, 0, stream>>>(W3, W4, W2, W3T, W4T, W2T);
  xyzprep_kernel<<<NPTS/256, 256, 0, stream>>>(xyz, xT);
  knn_kernel<<<NPTS, 256, 0, stream>>>(xyz, xT, idx, oxyz);
  h1_moments_kernel<<<NSAMP/512, 256, 0, stream>>>(xyz, idx, mbuck);
  bn_prep1<<<1, 128, 0, stream>>>(W1, b1, g1, be1, mbuck, misc);
  h2_kernel<<<NPTS/4, 256, 0, stream>>>(xyz, idx, W1, b1, W2T, b2, misc, h2, gmax);
  pgemm_kernel<<<256, 256, 0, stream>>>(gmax, W3T, Pg);
  gemm3_kernel<<<(NSAMP/128)*2, 512, 0, stream>>>(h2, Pg, W3T, b3, h3, s3buck);
  bn_prep3<<<1, 512, 0, stream>>>(g3, be3, s3buck, misc);
  gemm4_kernel<<<NPTS/4, 512, 0, stream>>>(h3, W4T, b4, misc, ofeat);
}

// Round 6
// 342.765 us; speedup vs baseline: 1.0473x; 1.0473x over previous
//
#include <hip/hip_runtime.h>
#include <float.h>

// Problem constants: B=2, N=4096, K=20, H=384
// Inputs: fp32 arrays (values bf16-quantized by harness). Output: fp32.
#define NPTS_B 4096
#define NPTS 8192            // B*N
#define KNN 20
#define NSAMP (NPTS*KNN)     // 163840

typedef __attribute__((ext_vector_type(8))) short bf16x8;
typedef __attribute__((ext_vector_type(4))) float f32x4;

// -------- bf16 helpers (internal staging only) --------
static __device__ __forceinline__ float bf2f(unsigned short u) {
  return __uint_as_float(((unsigned int)u) << 16);
}
static __device__ __forceinline__ unsigned short f2bf(float f) {
  unsigned int u = __float_as_uint(f);
  u += 0x7fffu + ((u >> 16) & 1u);
  return (unsigned short)(u >> 16);
}
// async global->LDS 16B: wave-uniform LDS base + lane*16.
static __device__ __forceinline__ void gl_lds16(const void* g, void* l) {
  __builtin_amdgcn_global_load_lds(
      (const __attribute__((address_space(1))) unsigned int*)g,
      (__attribute__((address_space(3))) unsigned int*)l, 16, 0, 0);
}

// ============================================================
// K0: weight prep — W3 -> W3T bf16 [n][k]; W4 -> W4T bf16 [n][k];
// W2 (128x256) -> W2T bf16 [n=256][k=128]. All values bf16-grid -> EXACT.
// ============================================================
__global__ __launch_bounds__(256) void wprep_kernel(const float* __restrict__ W3,
                                                    const float* __restrict__ W4,
                                                    const float* __restrict__ W2,
                                                    unsigned short* __restrict__ W3T,
                                                    unsigned short* __restrict__ W4T,
                                                    unsigned short* __restrict__ W2T) {
  int id = blockIdx.x * 256 + threadIdx.x;
  if (id < 512*512) {
    int n = id >> 9, k = id & 511;
    W3T[id] = f2bf(W3[k*512 + n]);
  } else if (id < 512*512 + 384*512) {
    int id2 = id - 512*512;
    int n = id2 >> 9, k = id2 & 511;
    W4T[id2] = f2bf(W4[k*384 + n]);
  } else {
    int id2 = id - (512*512 + 384*512);   // < 256*128
    int n = id2 >> 7, k = id2 & 127;
    W2T[id2] = f2bf(W2[k*256 + n]);
  }
}

// ============================================================
// K1a (R19): xyzprep — SoA transpose + squared-norm precompute.
// xT[b] layout: [0..4095]=x, [4096..]=y, [8192..]=z, [12288..]=sq.
// sq computed with the EXACT expression/order knn used in-kernel
// ((x*x+y*y)+z*z, contract off) -> bit-identical keys.
// ============================================================
__global__ __launch_bounds__(256) void xyzprep_kernel(const float* __restrict__ xyz,
                                                      float* __restrict__ xT) {
#pragma clang fp contract(off)
  int j = blockIdx.x * 256 + threadIdx.x;   // 0..8191
  int b = j >> 12, jj = j & 4095;
  float x = xyz[j*3+0], y = xyz[j*3+1], z = xyz[j*3+2];
  float sq = (x*x + y*y) + z*z;
  float* base = xT + (size_t)b*16384;
  base[jj] = x; base[4096+jj] = y; base[8192+jj] = z; base[12288+jj] = sq;
}

// ============================================================
// K1 (R19): KNN via radix-select + rank-sort (one block per point).
// Same u64 (d2_bits<<32|j) keys as the old extract-min (identical
// ordering/tie-break): histogram key[31:20] -> threshold bin -> compact
// (~30 items) -> O(n^2) rank-sort. ~5 barriers vs 20.
// ============================================================
__global__ __launch_bounds__(256) void knn_kernel(const float* __restrict__ xyz,
                                                  const float* __restrict__ xT,
                                                  int* __restrict__ idx,
                                                  float* __restrict__ out_xyz) {
#pragma clang fp contract(off)
  int p = blockIdx.x;            // 0..8191
  int b = p >> 12;
  int base = b << 12;            // batch base row
  int tid = threadIdx.x;
  const float* xb = xT + (size_t)b*16384;
  float xi0 = xyz[p*3+0], xi1 = xyz[p*3+1], xi2 = xyz[p*3+2];
  float sqi = (xi0*xi0 + xi1*xi1) + xi2*xi2;

  __shared__ __align__(16) int hist[4096];      // 16 KB; aliased by list later
  __shared__ int sL1[256];
  __shared__ int nsel, binB;

#pragma unroll
  for (int u = 0; u < 16; ++u) hist[tid + (u << 8)] = 0;
  if (tid == 0) nsel = 0;
  __syncthreads();

  unsigned long long cand[16];
#pragma unroll
  for (int u = 0; u < 16; ++u) {
    int j = tid + (u << 8);
    float a0 = xb[j], a1 = xb[4096 + j], a2 = xb[8192 + j];
    float sqj = xb[12288 + j];
    float dt  = (xi0*a0 + xi1*a1) + xi2*a2;
    float d2  = (sqi + sqj) - 2.0f*dt;
    unsigned int kb = __float_as_uint(d2);
    cand[u] = ((unsigned long long)kb << 32) | (unsigned int)j;
    atomicAdd(&hist[kb >> 20], 1);
  }
  __syncthreads();

  // level-1 sums: each thread sums its 16 consecutive bins
  {
    int s = 0;
#pragma unroll
    for (int u = 0; u < 16; ++u) s += hist[tid*16 + u];
    sL1[tid] = s;
  }
  __syncthreads();

  // wave 0: 64 lanes x 4 sL1 (64 bins each) -> inclusive scan -> find B
  if (tid < 64) {
    int v = sL1[tid*4] + sL1[tid*4+1] + sL1[tid*4+2] + sL1[tid*4+3];
    int incl = v;
#pragma unroll
    for (int off = 1; off < 64; off <<= 1) {
      int t = __shfl_up(incl, off);
      if (tid >= off) incl += t;
    }
    unsigned long long ball = __ballot(incl >= KNN);   // nonempty: lane63 = 4096
    int L = __ffsll(ball) - 1;
    if (tid == L) {
      int cum = incl - v;             // count in lanes < L
      int bfound = -1;
      for (int t2 = 4*L; t2 < 4*L + 4; ++t2) {
        int s = sL1[t2];
        if (bfound < 0) {
          if (cum + s >= KNN) {
            for (int u = 0; u < 16; ++u) {
              int c = hist[t2*16 + u];
              if (cum + c >= KNN) { bfound = t2*16 + u; break; }
              cum += c;
            }
          } else {
            cum += s;
          }
        }
      }
      binB = bfound;
    }
  }
  __syncthreads();

  int B = binB;
  unsigned long long* list = (unsigned long long*)hist;   // cap 2048 (16 KB)
#pragma unroll
  for (int u = 0; u < 16; ++u) {
    if ((int)(unsigned int)(cand[u] >> 52) <= B) {        // key>>20 == cand>>52
      int pos = atomicAdd(&nsel, 1);
      if (pos < 2048) list[pos] = cand[u];
    }
  }
  __syncthreads();

  int n = nsel; if (n > 2048) n = 2048;                   // n >= 20 guaranteed
  for (int t = tid; t < n; t += 256) {
    unsigned long long me = list[t];
    int rank = 0;
    for (int i = 0; i < n; ++i) rank += (list[i] < me);   // broadcast reads
    if (rank < KNN) idx[p*20 + rank] = base + (int)(me & 0xffffffffu);
  }
  if (tid < 3) out_xyz[p*3 + tid] = xyz[p*3 + tid];   // exact fp32 copy
}

// ============================================================
// K2: BN1 stats via 6-dim edge moments (affine trick).
// ============================================================
__global__ __launch_bounds__(256) void h1_moments_kernel(const float* __restrict__ xyz,
                                                         const int* __restrict__ idx,
                                                         float* __restrict__ mbuck) {
  int tid = threadIdx.x, blk = blockIdx.x;   // 320 blocks x 512 samples
  float A[33] = {};
#pragma unroll
  for (int u = 0; u < 2; ++u) {
    int s = blk*512 + (u << 8) + tid;
    unsigned int p = (unsigned int)s / 20u;
    int jg = idx[s];
    float c0 = xyz[p*3+0], c1 = xyz[p*3+1], c2 = xyz[p*3+2];
    float e[6];
    e[0] = xyz[jg*3+0] - c0; e[1] = xyz[jg*3+1] - c1; e[2] = xyz[jg*3+2] - c2;
    e[3] = c0; e[4] = c1; e[5] = c2;
    int k = 6;
#pragma unroll
    for (int d = 0; d < 6; ++d) {
      A[d] += e[d];
#pragma unroll
      for (int d2 = d; d2 < 6; ++d2) { A[k] = fmaf(e[d], e[d2], A[k]); ++k; }
    }
  }
#pragma unroll
  for (int off = 1; off < 64; off <<= 1) {
#pragma unroll
    for (int i = 0; i < 33; ++i) A[i] += __shfl_xor(A[i], off);
  }
  if ((tid & 63) == 0) {
    int b = ((blk << 2) | (tid >> 6)) & 15;
    for (int i = 0; i < 33; ++i) atomicAdd(&mbuck[b*64 + i], A[i]);
  }
}

__global__ void bn_prep1(const float* __restrict__ W1, const float* __restrict__ b1,
                         const float* __restrict__ g1, const float* __restrict__ be1,
                         const float* __restrict__ mbuck, float* __restrict__ misc) {
  __shared__ float red[33];
  int tid = threadIdx.x;  // 128
  if (tid < 33) {
    float s = 0.f;
    for (int b = 0; b < 16; ++b) s += mbuck[b*64 + tid];
    red[tid] = s;
  }
  __syncthreads();
  int c = tid;
  float w[6];
#pragma unroll
  for (int d = 0; d < 6; ++d) w[d] = W1[d*128 + c];
  const float inv = 1.0f / (float)NSAMP;
  float t = 0.f;
#pragma unroll
  for (int d = 0; d < 6; ++d) t = fmaf(w[d], red[d], t);
  t *= inv;
  float Q = 0.f;
  int k = 6;
#pragma unroll
  for (int d = 0; d < 6; ++d) {
#pragma unroll
    for (int d2 = d; d2 < 6; ++d2) {
      float coef = (d == d2) ? w[d]*w[d] : 2.f*w[d]*w[d2];
      Q = fmaf(coef, red[k], Q); ++k;
    }
  }
  Q *= inv;
  float var = Q - t*t;
  float mu = b1[c] + t;
  float a = g1[c] / sqrtf(var + 1e-5f);
  misc[c] = a;
  misc[128 + c] = be1[c] - mu*a;
}

// ============================================================
// K4: MFMA h2: per block of 4 points (M=80): edge -> h1 (BN1+ReLU, bf16
// into LDS A-tile) -> h2 = h1 @ W2T via MFMA (N=256, K=128) -> +b2 ->
// h2 bf16 store + fused per-point gmax.
// ============================================================
__global__ __launch_bounds__(256) void h2_kernel(const float* __restrict__ xyz,
                                                 const int* __restrict__ idx,
                                                 const float* __restrict__ W1,
                                                 const float* __restrict__ b1,
                                                 const unsigned short* __restrict__ W2T,
                                                 const float* __restrict__ b2,
                                                 const float* __restrict__ misc,
                                                 unsigned short* __restrict__ h2out,
                                                 unsigned short* __restrict__ gmaxout) {
  int p0 = blockIdx.x << 2;          // 4 points
  int tid = threadIdx.x;
  int w = tid >> 6, lane = tid & 63;
  int lr = lane & 15, lg = lane >> 4;
  __shared__ float e[80][6];
  __shared__ __align__(16) unsigned short As[80][136];
  __shared__ float pool[20][264];

  bf16x8 bfr[4][4];
#pragma unroll
  for (int j = 0; j < 4; ++j)
#pragma unroll
    for (int kk = 0; kk < 4; ++kk)
      bfr[j][kk] = *(const bf16x8*)(W2T + (size_t)(w*64 + j*16 + lr)*128 + kk*32 + lg*8);

  if (tid < 80) {
    int pl = (unsigned int)tid / 20u;
    int p = p0 + pl;
    int jg = idx[p0*20 + tid];
    float xi0 = xyz[p*3+0], xi1 = xyz[p*3+1], xi2 = xyz[p*3+2];
    e[tid][0] = xyz[jg*3+0] - xi0;
    e[tid][1] = xyz[jg*3+1] - xi1;
    e[tid][2] = xyz[jg*3+2] - xi2;
    e[tid][3] = xi0; e[tid][4] = xi1; e[tid][5] = xi2;
  }
  __syncthreads();

  {
    int c = tid & 127, half = tid >> 7;
    float w1v[6];
#pragma unroll
    for (int d = 0; d < 6; ++d) w1v[d] = W1[d*128 + c];
    float b1v = b1[c], a1 = misc[c], d1 = misc[128 + c];
#pragma unroll
    for (int u = 0; u < 40; ++u) {
      int row = (u << 1) | half;
      float v = b1v;
#pragma unroll
      for (int d = 0; d < 6; ++d) v = fmaf(e[row][d], w1v[d], v);
      v = fmaxf(fmaf(a1, v, d1), 0.f);
      As[row][c] = f2bf(v);
    }
  }
  __syncthreads();

  f32x4 acc[5][4] = {};
#pragma unroll
  for (int kk = 0; kk < 4; ++kk) {
    bf16x8 a[5];
#pragma unroll
    for (int i = 0; i < 5; ++i)
      a[i] = *(const bf16x8*)&As[i*16 + lr][kk*32 + lg*8];
#pragma unroll
    for (int i = 0; i < 5; ++i)
#pragma unroll
      for (int j = 0; j < 4; ++j)
        acc[i][j] = __builtin_amdgcn_mfma_f32_16x16x32_bf16(a[i], bfr[j][kk], acc[i][j], 0, 0, 0);
  }

  float b2v[4];
#pragma unroll
  for (int j = 0; j < 4; ++j) b2v[j] = b2[w*64 + j*16 + lr];
#pragma unroll
  for (int i = 0; i < 5; ++i) {
    int rbase = p0*20 + i*16 + lg*4;
#pragma unroll
    for (int j = 0; j < 4; ++j) {
      int col = w*64 + j*16 + lr;
      float v0 = acc[i][j][0] + b2v[j];
      float v1 = acc[i][j][1] + b2v[j];
      float v2 = acc[i][j][2] + b2v[j];
      float v3 = acc[i][j][3] + b2v[j];
      h2out[(size_t)(rbase+0)*256 + col] = f2bf(v0);
      h2out[(size_t)(rbase+1)*256 + col] = f2bf(v1);
      h2out[(size_t)(rbase+2)*256 + col] = f2bf(v2);
      h2out[(size_t)(rbase+3)*256 + col] = f2bf(v3);
      pool[i*4 + lg][col] = fmaxf(fmaxf(v0, v1), fmaxf(v2, v3));
    }
  }
  __syncthreads();
#pragma unroll
  for (int l = 0; l < 4; ++l) {
    int id = tid + (l << 8);        // 0..1023 : 4 points x 256 cols
    int q = id >> 8, col = id & 255;
    float v = pool[q*5][col];
#pragma unroll
    for (int u = 1; u < 5; ++u) v = fmaxf(v, pool[q*5 + u][col]);
    gmaxout[(size_t)(p0 + q)*256 + col] = f2bf(v);
  }
}

// ============================================================
// K5a (R18): pgemm — Pg = gmax @ W3a  (8192 x 512 x 256, bf16 MFMA).
// Computed once (256 blocks) instead of per-gemm3-block.
// ============================================================
__global__ __launch_bounds__(256) void pgemm_kernel(const unsigned short* __restrict__ gmax,
                                                    const unsigned short* __restrict__ W3T,
                                                    unsigned short* __restrict__ Pg) {
  int bid = blockIdx.x;             // 256 = 128 m * 2 n
  int bm = bid >> 1, bn = bid & 1;
  int m0 = bm << 6, n0 = bn << 8;
  int tid = threadIdx.x;
  int lane = tid & 63, w = tid >> 6;   // 4 waves, wave = n-column
  int lr = lane & 15, lg = lane >> 4;
  __shared__ __align__(16) char smem[40960];
  unsigned short (*As)[64] = (unsigned short (*)[64])smem;              // 64*64*2  = 8192
  unsigned short (*Bs)[64] = (unsigned short (*)[64])(smem + 8192);     // 256*64*2 = 32768
  unsigned short (*Cs)[264] = (unsigned short (*)[264])smem;            // 33792 (alias)

  int swz = lr >> 1;
  f32x4 acc[4][4] = {};
  for (int kc = 0; kc < 256; kc += 64) {
#pragma unroll
    for (int l = 0; l < 2; ++l) {
      int id = tid + (l << 8);
      int row = id >> 3, ks = id & 7, kg = ks ^ ((id >> 4) & 7);
      gl_lds16(gmax + (size_t)(m0 + row)*256 + kc + (kg << 3), &As[row][ks << 3]);
    }
#pragma unroll
    for (int l = 0; l < 8; ++l) {
      int id = tid + (l << 8);
      int row = id >> 3, ks = id & 7, kg = ks ^ ((id >> 4) & 7);
      gl_lds16(W3T + (size_t)(n0 + row)*512 + kc + (kg << 3), &Bs[row][ks << 3]);
    }
    __syncthreads();
#pragma unroll
    for (int h = 0; h < 2; ++h) {
      int ch = ((h << 2) | lg) ^ swz;
      bf16x8 a[4], b[4];
#pragma unroll
      for (int t = 0; t < 4; ++t)
        a[t] = *(const bf16x8*)&As[t*16 + lr][ch << 3];
#pragma unroll
      for (int t = 0; t < 4; ++t)
        b[t] = *(const bf16x8*)&Bs[w*64 + t*16 + lr][ch << 3];
#pragma unroll
      for (int i = 0; i < 4; ++i)
#pragma unroll
        for (int j = 0; j < 4; ++j)
          acc[i][j] = __builtin_amdgcn_mfma_f32_16x16x32_bf16(a[i], b[j], acc[i][j], 0, 0, 0);
    }
    __syncthreads();
  }
#pragma unroll
  for (int i = 0; i < 4; ++i)
#pragma unroll
    for (int j = 0; j < 4; ++j)
#pragma unroll
      for (int r = 0; r < 4; ++r)
        Cs[i*16 + lg*4 + r][w*64 + j*16 + lr] = f2bf(acc[i][j][r]);
  __syncthreads();
#pragma unroll
  for (int l = 0; l < 8; ++l) {
    int id = tid + (l << 8);          // 0..2047 : row = id>>5, chunk = id&31
    int row = id >> 5, chk = id & 31;
    *(uint4*)(Pg + (size_t)(m0 + row)*512 + n0 + (chk << 3)) =
        *(const uint4*)&Cs[row][chk << 3];
  }
}

// ============================================================
// K5: MFMA GEMM: h3 = h2 @ W3b + b3 + Pg (163840x512x256), bf16 MFMA.
// R21: min-2-phase software pipeline on the PURE main loop (R16/R17's
// attempt was contaminated by the swizzle bank bug + the P-phase; both
// are gone now). BK=32 double-buffer: As 2x[128][32] + Bs 2x[256][32]
// = 48 KB (+2 KB stats) -> 3 blocks/CU occupancy PRESERVED (m132
// cliff avoided). 8 iters, ONE barrier each; STAGE(t+1) issued before
// compute(t) so the barrier's implicit vmcnt(0) drains loads that aged
// through a full compute phase (~1800 cyc matrix work/CU > ~900 cyc
// HBM latency). Swizzle = R17-verified involution: store chunk
// kg = ks ^ ((row>>1)&3), read chunk lg ^ ((lr>>1)&3) (conflict-free).
// Epilogue (Pg add + stats + coalesced Cs store) unchanged from R18.
// ============================================================
__global__ __launch_bounds__(512, 4) void gemm3_kernel(const unsigned short* __restrict__ h2,
                                                       const unsigned short* __restrict__ Pg,
                                                       const unsigned short* __restrict__ W3T,
                                                       const float* __restrict__ b3,
                                                       unsigned short* __restrict__ h3,
                                                       float* __restrict__ s3buck) {
  int bid = blockIdx.x;               // 2560 = 160 grp * (2 bn * 8 x)
  int grp = bid >> 4, rem = bid & 15;
  int bn = rem >> 3;                  // 0..1
  int bm = (grp << 3) | (rem & 7);    // 0..1279
  int m0 = bm << 7, n0 = bn << 8;
  int tid = threadIdx.x;
  int lane = tid & 63, w = tid >> 6;  // 8 waves
  int mw = w >> 2, nw = w & 3;        // 2m x 4n
  int lr = lane & 15, lg = lane >> 4;
  __shared__ __align__(16) char smem[51200];
  unsigned short (*As)[128][32] = (unsigned short (*)[128][32])smem;            // 2*8192  = 16384 B
  unsigned short (*Bs)[256][32] = (unsigned short (*)[256][32])(smem + 16384);  // 2*16384 = 32768 B
  float* ssum = (float*)(smem + 49152);                                 // 1024 B
  float* ssq  = ssum + 256;                                             // 1024 B -> 51200
  unsigned short (*Cs)[264] = (unsigned short (*)[264])smem;            // 33792 B (aliases As+Bs)

  // staging coords: 1 A-load + 2 B-loads per thread per K-chunk.
  // row = tid>>2 (A: 0..127; B adds +128 for 2nd load), phys kseg = tid&3,
  // global kseg = phys ^ ((row>>1)&3) = phys ^ ((tid>>3)&3)
  int arow = tid >> 2, aks = tid & 3, akg = aks ^ ((tid >> 3) & 3);

  // STAGE(u): K-chunk u (0..7) into buffer u&1. A=h2, B=W3T k 256..511.
  auto STAGE = [&](int u) {
    int buf = u & 1;
    int kc = u << 5;
    gl_lds16(h2 + (size_t)(m0 + arow)*256 + kc + (akg << 3),
             &As[buf][arow][aks << 3]);
#pragma unroll
    for (int l = 0; l < 2; ++l) {
      int id = tid + (l << 9);
      int brow = id >> 2, bks = id & 3, bkg = bks ^ ((id >> 3) & 3);
      gl_lds16(W3T + (size_t)(n0 + brow)*512 + 256 + kc + (bkg << 3),
               &Bs[buf][brow][bks << 3]);
    }
  };

  int ch = (lg ^ ((lr >> 1) & 3)) << 3;   // swizzled read chunk (elements)

  STAGE(0);
  __syncthreads();

  // ---- pipelined main loop: h3-partial = h2 @ W3b (K = 256..511) ----
  f32x4 acc[4][4] = {};
  for (int t = 0; t < 8; ++t) {
    if (t < 7) STAGE(t + 1);
    int cur = t & 1;
    bf16x8 a[4], b[4];
#pragma unroll
    for (int i = 0; i < 4; ++i)
      a[i] = *(const bf16x8*)&As[cur][mw*64 + i*16 + lr][ch];
#pragma unroll
    for (int j = 0; j < 4; ++j)
      b[j] = *(const bf16x8*)&Bs[cur][nw*64 + j*16 + lr][ch];
#pragma unroll
    for (int i = 0; i < 4; ++i)
#pragma unroll
      for (int j = 0; j < 4; ++j)
        acc[i][j] = __builtin_amdgcn_mfma_f32_16x16x32_bf16(a[i], b[j], acc[i][j], 0, 0, 0);
    __syncthreads();                  // drains STAGE(t+1) loads (aged a full compute phase)
  }

  // ---- Epilogue: v = acc + b3 + Pg[pt]; stats; COALESCED store via Cs ----
  if (tid < 256) { ssum[tid] = 0.f; ssq[tid] = 0.f; }
  __syncthreads();
  unsigned int pt[4][4];
#pragma unroll
  for (int i = 0; i < 4; ++i) {
    int rbase = m0 + mw*64 + i*16 + lg*4;
#pragma unroll
    for (int r = 0; r < 4; ++r)
      pt[i][r] = (unsigned int)(rbase + r) / 20u;
  }
#pragma unroll
  for (int half = 0; half < 2; ++half) {
    if (mw == half) {
#pragma unroll
      for (int j = 0; j < 4; ++j) {
        int colL = nw*64 + j*16 + lr;
        float b3v = b3[n0 + colL];
        float sumv = 0.f, sqv = 0.f;
#pragma unroll
        for (int i = 0; i < 4; ++i) {
#pragma unroll
          for (int r = 0; r < 4; ++r) {
            float v = acc[i][j][r] + b3v +
                      bf2f(Pg[(size_t)pt[i][r]*512 + n0 + colL]);
            Cs[i*16 + lg*4 + r][colL] = f2bf(v);
            sumv += v; sqv = fmaf(v, v, sqv);
          }
        }
        sumv += __shfl_xor(sumv, 16); sumv += __shfl_xor(sumv, 32);
        sqv  += __shfl_xor(sqv, 16);  sqv  += __shfl_xor(sqv, 32);
        if (lg == 0) {
          atomicAdd(&ssum[colL], sumv);
          atomicAdd(&ssq[colL], sqv);
        }
      }
    }
    __syncthreads();
#pragma unroll
    for (int l = 0; l < 4; ++l) {
      int id = tid + (l << 9);          // 0..2047 : row = id>>5, chunk = id&31
      int row = id >> 5, chk = id & 31;
      *(uint4*)(h3 + (size_t)(m0 + half*64 + row)*512 + n0 + (chk << 3)) =
          *(const uint4*)&Cs[row][chk << 3];
    }
    __syncthreads();
  }
  if (tid < 256) {
    int bkt = (bid & 63) * 1024;
    atomicAdd(&s3buck[bkt + n0 + tid], ssum[tid]);
    atomicAdd(&s3buck[bkt + 512 + n0 + tid], ssq[tid]);
  }
}

__global__ void bn_prep3(const float* __restrict__ g3, const float* __restrict__ be3,
                         const float* __restrict__ s3buck, float* __restrict__ misc) {
  int c = threadIdx.x;  // 512
  float s = 0.f, q = 0.f;
  for (int b = 0; b < 64; ++b) { s += s3buck[b*1024 + c]; q += s3buck[b*1024 + 512 + c]; }
  const float inv = 1.0f / (float)NSAMP;
  float mu = s * inv;
  float var = q * inv - mu * mu;
  float a = g3[c] / sqrtf(var + 1e-5f);
  misc[256 + c] = a;
  misc[768 + c] = be3[c] - mu * a;
}

// ============================================================
// K7: MFMA GEMM: h4 = relu(a3*h3+d3) @ W4 (+b4), fused max-pool over K=20.
// R20: gemm3's BK=64 body ported (8 iters, 30 MFMA/wave/iter, both-side
// XOR swizzle) — dropped gemm4 from 91.5 to <85 µs, conflicts ~0.
// ============================================================
__global__ __launch_bounds__(512, 4) void gemm4_kernel(const unsigned short* __restrict__ h3,
                                                       const unsigned short* __restrict__ W4T,
                                                       const float* __restrict__ b4,
                                                       const float* __restrict__ misc,
                                                       float* __restrict__ outf) {
  int bm = blockIdx.x;              // 2048 blocks: 4 points each
  int m0 = bm * 80;
  int tid = threadIdx.x;
  int lane = tid & 63, w = tid >> 6;     // w = column wave 0..7
  int lr = lane & 15, lg = lane >> 4;
  __shared__ __align__(16) char smem[63488];
  unsigned short (*As)[64] = (unsigned short (*)[64])smem;            // 80*128  = 10240 B
  unsigned short (*Bs)[64] = (unsigned short (*)[64])(smem + 10240);  // 384*128 = 49152 B -> 59392
  float (*pool)[392] = (float (*)[392])smem;                          // 31360 B (alias)
  float* af = (float*)(smem + 59392);                                 // 512 f32
  float* df = af + 512;                                               // 512 f32  -> ends 63488
  if (tid < 512) {
    af[tid] = misc[256 + tid];
    df[tid] = misc[768 + tid];
  }
  __syncthreads();
  f32x4 acc[5][3] = {};

  // A staging coords: 640 uint4/iter (80 rows x 8 chunks).
  // aR0: chunk tid (rows 0..63); aR1: chunk 512+tid, tid<128 (rows 64..79).
  int arow = tid >> 3, aks = tid & 7, akg = aks ^ ((tid >> 4) & 7);
  uint4 aR0, aR1;
  aR0 = *(const uint4*)(h3 + (size_t)(m0 + arow)*512 + (akg << 3));
  if (tid < 128)
    aR1 = *(const uint4*)(h3 + (size_t)(m0 + 64 + arow)*512 + (akg << 3));

  for (int kc = 0; kc < 512; kc += 64) {
    // --- stage B: 384 rows x 8 chunks = 3072 gl_lds16, XOR-swizzled ---
#pragma unroll
    for (int l = 0; l < 6; ++l) {
      int id = tid + (l << 9);
      int row = id >> 3, ks = id & 7, kg = ks ^ ((id >> 4) & 7);
      gl_lds16(W4T + (size_t)row*512 + kc + (kg << 3), &Bs[row][ks << 3]);
    }
    // --- stage A: dequant BN3 affine + relu, repack bf16, swizzled ---
    {
      int k0 = kc + (akg << 3);
      unsigned int o[4];
#pragma unroll
      for (int q = 0; q < 4; ++q) {
        unsigned int u = ((const unsigned int*)&aR0)[q];
        float lo = bf2f((unsigned short)(u & 0xffffu));
        float hi = bf2f((unsigned short)(u >> 16));
        lo = fmaxf(fmaf(af[k0 + q*2],     lo, df[k0 + q*2]),     0.f);
        hi = fmaxf(fmaf(af[k0 + q*2 + 1], hi, df[k0 + q*2 + 1]), 0.f);
        o[q] = (unsigned int)f2bf(lo) | ((unsigned int)f2bf(hi) << 16);
      }
      *(uint4*)&As[arow][aks << 3] = *(const uint4*)o;
      if (tid < 128) {
        unsigned int o1[4];
#pragma unroll
        for (int q = 0; q < 4; ++q) {
          unsigned int u = ((const unsigned int*)&aR1)[q];
          float lo = bf2f((unsigned short)(u & 0xffffu));
          float hi = bf2f((unsigned short)(u >> 16));
          lo = fmaxf(fmaf(af[k0 + q*2],     lo, df[k0 + q*2]),     0.f);
          hi = fmaxf(fmaf(af[k0 + q*2 + 1], hi, df[k0 + q*2 + 1]), 0.f);
          o1[q] = (unsigned int)f2bf(lo) | ((unsigned int)f2bf(hi) << 16);
        }
        *(uint4*)&As[64 + arow][aks << 3] = *(const uint4*)o1;
      }
    }
    __syncthreads();
    // --- prefetch next A ---
    int kn = kc + 64;
    if (kn < 512) {
      aR0 = *(const uint4*)(h3 + (size_t)(m0 + arow)*512 + kn + (akg << 3));
      if (tid < 128)
        aR1 = *(const uint4*)(h3 + (size_t)(m0 + 64 + arow)*512 + kn + (akg << 3));
    }
    // --- fragments + MFMA: 2 halves x 15 ---
#pragma unroll
    for (int h = 0; h < 2; ++h) {
      int ch = ((h << 2) | lg) ^ (lr >> 1);
      bf16x8 a[5], b[3];
#pragma unroll
      for (int t = 0; t < 5; ++t)
        a[t] = *(const bf16x8*)&As[t*16 + lr][ch << 3];
#pragma unroll
      for (int t = 0; t < 3; ++t)
        b[t] = *(const bf16x8*)&Bs[w*48 + t*16 + lr][ch << 3];
#pragma unroll
      for (int i = 0; i < 5; ++i)
#pragma unroll
        for (int j = 0; j < 3; ++j)
          acc[i][j] = __builtin_amdgcn_mfma_f32_16x16x32_bf16(a[i], b[j], acc[i][j], 0, 0, 0);
    }
    __syncthreads();
  }

  // fused max-pool: per-lane reg-max (4 rows, point-pure since 4|20)
#pragma unroll
  for (int i = 0; i < 5; ++i)
#pragma unroll
    for (int j = 0; j < 3; ++j) {
      float m = fmaxf(fmaxf(acc[i][j][0], acc[i][j][1]),
                      fmaxf(acc[i][j][2], acc[i][j][3]));
      pool[i*4 + lg][w*48 + j*16 + lr] = m;
    }
  __syncthreads();
#pragma unroll
  for (int l = 0; l < 3; ++l) {
    int id = tid + (l << 9);            // 0..1535 : 4 points x 384 cols
    int q = id / 384, c = id - q*384;
    float v = pool[q*5][c];
#pragma unroll
    for (int u = 1; u < 5; ++u) v = fmaxf(v, pool[q*5 + u][c]);
    outf[(size_t)(bm*4 + q)*384 + c] = v + b4[c];
  }
}

// ============================================================
// Workspace layout:
//   0x0000000  idx        640 KB
//   0x00A0000  misc       1280 f32
//   0x00A2000  mbuck      16*64 f32 = 4 KB (zeroed)
//   0x00AA000  s3buck     256 KB  (zeroed)
//   0x00F0000  W3T bf16   512 KB
//   0x0170000  W4T bf16   384 KB
//   0x01D0000  W2T bf16   64 KB
//   0x0200000  gmax bf16  4 MB
//   0x0600000  h2   bf16  80 MB
//   0x5600000  h3   bf16  160 MB
//   0xF600000  Pg   bf16  8 MB
//   0xFE00000  xT   f32   128 KB  -> end 0xFE20000
// ============================================================
extern "C" void kernel_launch(void* const* d_in, const int* in_sizes, int n_in,
                              void* d_out, int out_size, void* d_ws, size_t ws_size,
                              hipStream_t stream) {
  const float* xyz = (const float*)d_in[0];
  const float* W1  = (const float*)d_in[1];
  const float* b1  = (const float*)d_in[2];
  const float* g1  = (const float*)d_in[3];
  const float* be1 = (const float*)d_in[4];
  const float* W2  = (const float*)d_in[5];
  const float* b2  = (const float*)d_in[6];
  const float* W3  = (const float*)d_in[7];
  const float* b3  = (const float*)d_in[8];
  const float* g3  = (const float*)d_in[9];
  const float* be3 = (const float*)d_in[10];
  const float* W4  = (const float*)d_in[11];
  const float* b4  = (const float*)d_in[12];

  char* ws = (char*)d_ws;
  int*            idx    = (int*)ws;
  float*          misc   = (float*)(ws + 0xA0000);
  float*          mbuck  = (float*)(ws + 0xA2000);
  float*          s3buck = (float*)(ws + 0xAA000);
  unsigned short* W3T    = (unsigned short*)(ws + 0xF0000);
  unsigned short* W4T    = (unsigned short*)(ws + 0x170000);
  unsigned short* W2T    = (unsigned short*)(ws + 0x1D0000);
  unsigned short* gmax   = (unsigned short*)(ws + 0x200000);
  unsigned short* h2     = (unsigned short*)(ws + 0x600000);
  unsigned short* h3     = (unsigned short*)(ws + 0x5600000ULL);
  unsigned short* Pg     = (unsigned short*)(ws + 0xF600000ULL);
  float*          xT     = (float*)(ws + 0xFE00000ULL);

  float* ofp   = (float*)d_out;
  float* oxyz  = ofp;             // 24576 fp32
  float* ofeat = ofp + 24576;     // 8192*384 fp32

  hipMemsetAsync(ws + 0xA2000, 0, 0x48000, stream);   // zero mbuck + s3buck

  wprep_kernel<<<(512*512 + 384*512 + 256*128)/256, 256, 0, stream>>>(W3, W4, W2, W3T, W4T, W2T);
  xyzprep_kernel<<<NPTS/256, 256, 0, stream>>>(xyz, xT);
  knn_kernel<<<NPTS, 256, 0, stream>>>(xyz, xT, idx, oxyz);
  h1_moments_kernel<<<NSAMP/512, 256, 0, stream>>>(xyz, idx, mbuck);
  bn_prep1<<<1, 128, 0, stream>>>(W1, b1, g1, be1, mbuck, misc);
  h2_kernel<<<NPTS/4, 256, 0, stream>>>(xyz, idx, W1, b1, W2T, b2, misc, h2, gmax);
  pgemm_kernel<<<256, 256, 0, stream>>>(gmax, W3T, Pg);
  gemm3_kernel<<<(NSAMP/128)*2, 512, 0, stream>>>(h2, Pg, W3T, b3, h3, s3buck);
  bn_prep3<<<1, 512, 0, stream>>>(g3, be3, s3buck, misc);
  gemm4_kernel<<<NPTS/4, 512, 0, stream>>>(h3, W4T, b4, misc, ofeat);
}